// Round 8
// baseline (119.067 us; speedup 1.0000x reference)
//
#include <hip/hip_runtime.h>

typedef short short8 __attribute__((ext_vector_type(8)));
typedef float f32x4 __attribute__((ext_vector_type(4)));

#define NN 4096
#define NE 512
#define HD 64
#define KROWS 4288   // 64 pad + 4096 + 128 pad (per batch)
#define KOFF  64

// --- bf16 helpers: truncation hi/lo split; hi+lo == f to ~2^-17 rel ---
__device__ __forceinline__ unsigned short bf_trunc(float f) {
    union { float f; unsigned u; } c; c.f = f;
    return (unsigned short)(c.u >> 16);
}
__device__ __forceinline__ void bf_split(float f, unsigned short& hi, unsigned short& lo) {
    union { float f; unsigned u; } c; c.f = f;
    unsigned uh = c.u & 0xFFFF0000u;
    hi = (unsigned short)(uh >> 16);
    union { float f; unsigned u; } d; d.u = uh;
    lo = bf_trunc(f - d.f);
}

#define MFMA16(a, b, c) __builtin_amdgcn_mfma_f32_16x16x32_bf16((a), (b), (c), 0, 0, 0)

// ---------------------------------------------------------------------------
// wprep: (a) W=[Wq|Wk|Wv] (512x192) -> B-frag order hi/lo.
//        (b) zero K-buffer pad rows + Vs.
//        (c) init Vf: zeros everywhere, ones-pattern in nt=4 hi plane
//            (proj fills the nt<4 V-frag planes itself).
// W frag layout: [kt(16)][nt(12)][lane(64)][j(8)]
// Vf layout:     [b(2)][jt(5)][nt(5)][lane(64)][jj(8)]
// ---------------------------------------------------------------------------
__global__ __launch_bounds__(256) void wprep_kernel(
    const float* __restrict__ Wq, const float* __restrict__ Wk,
    const float* __restrict__ Wv,
    unsigned short* __restrict__ Wfhi, unsigned short* __restrict__ Wflo,
    unsigned short* __restrict__ Khi, unsigned short* __restrict__ Klo,
    unsigned short* __restrict__ Vfhi, unsigned short* __restrict__ Vflo,
    float* __restrict__ Vs)
{
    const int gtid = blockIdx.x * 256 + threadIdx.x;   // [0, 12288)
    const int L = gtid & 63;
    {
        const int nt = (gtid >> 6) % 12;
        const int kt = gtid / 768;
        const int n = nt * 16 + (L & 15);
        const int kbase = kt * 32 + (L >> 4) * 8;
        const float* src; int col;
        if (n < 64)       { src = Wq; col = n; }
        else if (n < 128) { src = Wk; col = n - 64; }
        else              { src = Wv; col = n - 128; }
        short8 sh, sl;
#pragma unroll
        for (int j = 0; j < 8; ++j) {
            unsigned short h, l;
            bf_split(src[(size_t)(kbase + j) * HD + col], h, l);
            sh[j] = (short)h; sl[j] = (short)l;
        }
        *(short8*)(Wfhi + (size_t)gtid * 8) = sh;
        *(short8*)(Wflo + (size_t)gtid * 8) = sl;
    }
    if (gtid < 6144) {   // zero 768 pad rows x 128 B (hi+lo)
        const int p = gtid >> 3, o = gtid & 7;
        const int b = p / 192, q = p - b * 192;
        const size_t row = (size_t)b * KROWS + (q < 64 ? q : 4096 + q);
        const short8 z = {0, 0, 0, 0, 0, 0, 0, 0};
        *(short8*)(Khi + row * HD + o * 8) = z;
        *(short8*)(Klo + row * HD + o * 8) = z;
    }
    if (gtid < 3200) {   // Vf init: zeros; nt==4 hi plane gets ones-pattern
        const int rem = gtid % 1600;
        const int jt = rem / 320;
        const int nt = (rem / 64) % 5;
        short8 sh = {0, 0, 0, 0, 0, 0, 0, 0};
        const short8 z = {0, 0, 0, 0, 0, 0, 0, 0};
        if (nt == 4 && (L & 15) == 0) {
#pragma unroll
            for (int jj = 0; jj < 8; ++jj) {
                const int j = jt * 32 + (L >> 4) * 8 + jj;
                if (j < 129) sh[jj] = (short)0x3F80;   // bf16(1.0)
            }
        }
        *(short8*)(Vfhi + (size_t)gtid * 8) = sh;
        *(short8*)(Vflo + (size_t)gtid * 8) = z;
    }
    if (gtid < 128) Vs[gtid] = 0.f;
}

// ---------------------------------------------------------------------------
// proj: QKV = x @ W + b, 3-pass bf16 MFMA (ahi*Whi + alo*Whi + ahi*Wlo).
// grid 128 x 512 (8 waves): 64 ROWS/BLOCK -> W-frag traffic amortized 4x
// vs 16-row blocks (aggregate 49 MB). Wave = rowtile (w>>1) x colhalf
// (w&1, 6 ntiles). Depth-1 prefetch under full unroll (SSA renaming,
// no copy chain). 18 MFMA per kt-step per wave.
// Epilogue: Q/K stores; V -> LDS; Vsum; blocks covering rows 0..128 emit
// V-frags directly.
// ---------------------------------------------------------------------------
__global__ __launch_bounds__(512) void proj_kernel(
    const float* __restrict__ x,
    const unsigned short* __restrict__ Wfhi, const unsigned short* __restrict__ Wflo,
    const float* __restrict__ bq, const float* __restrict__ bk,
    const float* __restrict__ bv,
    unsigned short* __restrict__ Qhi, unsigned short* __restrict__ Qlo,
    unsigned short* __restrict__ Khi, unsigned short* __restrict__ Klo,
    unsigned short* __restrict__ Vfhi, unsigned short* __restrict__ Vflo,
    float* __restrict__ Vs)
{
    __shared__ float V_lds[64][68];
    const int tid = threadIdx.x;
    const int L = tid & 63;
    const int w = tid >> 6;              // wave 0..7
    const int m = L & 15, kg = L >> 4;
    const int blk = blockIdx.x;          // 0..127
    const int r0 = blk * 64;
    const int b = blk >> 6;
    const int rowbase = r0 + (w >> 1) * 16;
    const int ch = (w & 1) * 6;          // first of 6 ntiles

    const float* xp = x + (size_t)(rowbase + m) * NE + kg * 8;

    f32x4 acc[6];
#pragma unroll
    for (int t = 0; t < 6; ++t) acc[t] = (f32x4){0.f, 0.f, 0.f, 0.f};

    // preload kt = 0
    float4 xa0 = *(const float4*)(xp);
    float4 xa1 = *(const float4*)(xp + 4);
    short8 wh[6], wl[6];
#pragma unroll
    for (int t = 0; t < 6; ++t) {
        wh[t] = *(const short8*)(Wfhi + (size_t)(ch + t) * 512 + L * 8);
        wl[t] = *(const short8*)(Wflo + (size_t)(ch + t) * 512 + L * 8);
    }

#pragma unroll
    for (int kt = 0; kt < 16; ++kt) {
        float4 xb0, xb1;
        short8 nh[6], nl[6];
        if (kt < 15) {                   // constant-folded under full unroll
            xb0 = *(const float4*)(xp + (kt + 1) * 32);
            xb1 = *(const float4*)(xp + (kt + 1) * 32 + 4);
#pragma unroll
            for (int t = 0; t < 6; ++t) {
                nh[t] = *(const short8*)(Wfhi + (size_t)((kt + 1) * 12 + ch + t) * 512 + L * 8);
                nl[t] = *(const short8*)(Wflo + (size_t)((kt + 1) * 12 + ch + t) * 512 + L * 8);
            }
        }
        const float xv[8] = {xa0.x, xa0.y, xa0.z, xa0.w,
                             xa1.x, xa1.y, xa1.z, xa1.w};
        short8 ahi, alo;
#pragma unroll
        for (int j = 0; j < 8; ++j) {
            unsigned short h, l; bf_split(xv[j], h, l);
            ahi[j] = (short)h; alo[j] = (short)l;
        }
#pragma unroll
        for (int t = 0; t < 6; ++t) {
            acc[t] = MFMA16(ahi, wh[t], acc[t]);
            acc[t] = MFMA16(alo, wh[t], acc[t]);
            acc[t] = MFMA16(ahi, wl[t], acc[t]);
        }
        if (kt < 15) {
            xa0 = xb0; xa1 = xb1;
#pragma unroll
            for (int t = 0; t < 6; ++t) { wh[t] = nh[t]; wl[t] = nl[t]; }
        }
    }

    // ---- epilogue: Q/K stores, V -> LDS ----
#pragma unroll
    for (int t = 0; t < 6; ++t) {
        const int nt = ch + t;
        const int cgc = nt * 16 + m;     // global col 0..191
        const float bias = (cgc < 64) ? bq[cgc]
                         : (cgc < 128) ? bk[cgc - 64] : bv[cgc - 128];
#pragma unroll
        for (int r = 0; r < 4; ++r) {
            const int gr = rowbase + kg * 4 + r;
            const float val = acc[t][r] + bias;
            if (cgc < 64) {
                unsigned short h, l; bf_split(val, h, l);
                Qhi[(size_t)gr * HD + cgc] = h;
                Qlo[(size_t)gr * HD + cgc] = l;
            } else if (cgc < 128) {
                const int d = cgc - 64, n = gr & 4095;
                const size_t idx = ((size_t)b * KROWS + KOFF + n) * HD + d;
                unsigned short h, l; bf_split(val, h, l);
                Khi[idx] = h; Klo[idx] = l;
            } else {
                V_lds[(w >> 1) * 16 + kg * 4 + r][cgc - 128] = val;
            }
        }
    }
    __syncthreads();

    // Vsum: one atomic per dim
    if (tid < 64) {
        float s = 0.f;
#pragma unroll
        for (int r = 0; r < 64; ++r) s += V_lds[r][tid];
        atomicAdd(&Vs[b * HD + tid], s);
    }

    // V-frag emission for rows < 129 (replaces vprep kernel):
    // frag (jt, nt): lane L holds V[j = jt*32 + kg*8 + jj][nt*16 + m].
    {
        const int local = blk & 63;      // block-in-batch; rows local*64..+63
        if (local < 2) {
            // local 0 -> jt {0,1}; local 1 -> jt {2,3}; all 8 waves used
            const int jt = local * 2 + (w >> 2);
            const int nt = w & 3;
            short8 sh, sl;
#pragma unroll
            for (int jj = 0; jj < 8; ++jj) {
                const int lrow = (w >> 2) * 32 + kg * 8 + jj;  // j - local*64
                unsigned short hh, ll;
                bf_split(V_lds[lrow][nt * 16 + m], hh, ll);
                sh[jj] = (short)hh; sl[jj] = (short)ll;
            }
            const size_t fo = ((size_t)((b * 25 + jt * 5 + nt) * 64 + L)) * 8;
            *(short8*)(Vfhi + fo) = sh;
            *(short8*)(Vflo + fo) = sl;
        } else if (local == 2 && w < 4) {
            // jt = 4: only j == 128 (kg==0, jj==0) is a real value
            const int nt = w;
            short8 sh = {0, 0, 0, 0, 0, 0, 0, 0};
            short8 sl = {0, 0, 0, 0, 0, 0, 0, 0};
            if (kg == 0) {
                unsigned short hh, ll;
                bf_split(V_lds[0][nt * 16 + m], hh, ll);
                sh[0] = (short)hh; sl[0] = (short)ll;
            }
            const size_t fo = ((size_t)((b * 25 + 4 * 5 + nt) * 64 + L)) * 8;
            *(short8*)(Vfhi + fo) = sh;
            *(short8*)(Vflo + fo) = sl;
        }
    }
}

// ---------------------------------------------------------------------------
// attn: grid 512 (b = blk>>8, 16 queries/block), block 256 (4 waves).
// ALL global loads issued up front into registers -> one latency hop.
// Phase 1: S = Q.K^T (3-pass), w = exp(s)-1 -> LDS (q,j) hi/lo.
// Phase 2: [out|den] = wt(16x160) @ [V|1|0] (3-pass); wave wv owns ntile wv;
// wave 0 also the ones-column (denominator) tile.
// ---------------------------------------------------------------------------
__global__ __launch_bounds__(256) void attn_kernel(
    const unsigned short* __restrict__ Qhi, const unsigned short* __restrict__ Qlo,
    const unsigned short* __restrict__ Khi, const unsigned short* __restrict__ Klo,
    const unsigned short* __restrict__ Vfhi, const unsigned short* __restrict__ Vflo,
    const float* __restrict__ Vs, float* __restrict__ out)
{
    __shared__ __align__(16) unsigned short wt_hi[16 * 168];
    __shared__ __align__(16) unsigned short wt_lo[16 * 168];
    __shared__ float den_lds[16];

    const int tid = threadIdx.x;
    const int L = tid & 63;
    const int w = tid >> 6;
    const int m = L & 15, kg = L >> 4;
    const int b = blockIdx.x >> 8;
    const int n0 = (blockIdx.x & 255) * 16;

    // ---- upfront load issuance (all independent) ----
    const unsigned short* qp  = Qhi + ((size_t)(b * NN + n0 + m)) * HD + kg * 8;
    const unsigned short* qp2 = Qlo + ((size_t)(b * NN + n0 + m)) * HD + kg * 8;
    const short8 qhi0 = *(const short8*)(qp);
    const short8 qhi1 = *(const short8*)(qp + 32);
    const short8 qlo0 = *(const short8*)(qp2);
    const short8 qlo1 = *(const short8*)(qp2 + 32);

    int kts[3]; int nkt;
    if (w == 3) { kts[0] = 3; kts[1] = 7; kts[2] = 8; nkt = 3; }
    else        { kts[0] = w; kts[1] = w + 4; kts[2] = 0; nkt = 2; }

    const unsigned short* KB  = Khi + (size_t)b * KROWS * HD;
    const unsigned short* KB2 = Klo + (size_t)b * KROWS * HD;
    short8 kh0[3], kh1[3], kl0[3], kl1[3];
#pragma unroll
    for (int i = 0; i < 3; ++i) {
        if (i < nkt) {                   // wave-uniform branch
            const size_t krow = (size_t)(n0 + kts[i] * 16 + m);
            const unsigned short* kp  = KB  + krow * HD + kg * 8;
            const unsigned short* kp2 = KB2 + krow * HD + kg * 8;
            kh0[i] = *(const short8*)(kp);
            kh1[i] = *(const short8*)(kp + 32);
            kl0[i] = *(const short8*)(kp2);
            kl1[i] = *(const short8*)(kp2 + 32);
        }
    }

    short8 vhi[5], vlo[5], vh4[5];
#pragma unroll
    for (int jt = 0; jt < 5; ++jt) {
        const size_t fo = ((size_t)((b * 25 + jt * 5 + w) * 64 + L)) * 8;
        vhi[jt] = *(const short8*)(Vfhi + fo);
        vlo[jt] = *(const short8*)(Vflo + fo);
    }
    if (w == 0) {                        // wave-uniform
#pragma unroll
        for (int jt = 0; jt < 5; ++jt) {
            const size_t fo4 = ((size_t)((b * 25 + jt * 5 + 4) * 64 + L)) * 8;
            vh4[jt] = *(const short8*)(Vfhi + fo4);
        }
    }

    // zero the (q,j) weight buffer (j in [129,168) must read as 0)
    for (int i = tid; i < (16 * 168) / 2; i += 256) {
        ((int*)wt_hi)[i] = 0;
        ((int*)wt_lo)[i] = 0;
    }
    __syncthreads();

    // ---- phase 1 ----
#pragma unroll
    for (int i = 0; i < 3; ++i) {
        if (i < nkt) {
            f32x4 acc = (f32x4){0.f, 0.f, 0.f, 0.f};
            acc = MFMA16(qhi0, kh0[i], acc);
            acc = MFMA16(qhi1, kh1[i], acc);
            acc = MFMA16(qlo0, kh0[i], acc);
            acc = MFMA16(qlo1, kh1[i], acc);
            acc = MFMA16(qhi0, kl0[i], acc);
            acc = MFMA16(qhi1, kl1[i], acc);
            const int l = kts[i] * 16 + m;
#pragma unroll
            for (int r = 0; r < 4; ++r) {
                const int q = kg * 4 + r;
                const int j = l - q;
                if (j >= 0 && j < 129) {
                    const float wval = __expf(acc[r]) - 1.0f;
                    unsigned short h, lo2; bf_split(wval, h, lo2);
                    wt_hi[q * 168 + j] = h;
                    wt_lo[q * 168 + j] = lo2;
                }
            }
        }
    }
    __syncthreads();

    // ---- phase 2 ----
    f32x4 oacc = (f32x4){0.f, 0.f, 0.f, 0.f};
    f32x4 dacc = (f32x4){0.f, 0.f, 0.f, 0.f};
#pragma unroll
    for (int jt = 0; jt < 5; ++jt) {
        const short8 whi = *(const short8*)(wt_hi + m * 168 + jt * 32 + kg * 8);
        const short8 wlo = *(const short8*)(wt_lo + m * 168 + jt * 32 + kg * 8);
        oacc = MFMA16(whi, vhi[jt], oacc);
        oacc = MFMA16(wlo, vhi[jt], oacc);
        oacc = MFMA16(whi, vlo[jt], oacc);
        if (w == 0) {
            dacc = MFMA16(whi, vh4[jt], dacc);
            dacc = MFMA16(wlo, vh4[jt], dacc);
        }
    }
    if (w == 0 && m == 0) {
#pragma unroll
        for (int r = 0; r < 4; ++r) den_lds[kg * 4 + r] = dacc[r];
    }
    __syncthreads();

    // ---- epilogue ----
    {
        const float vs = Vs[b * HD + w * 16 + m];
#pragma unroll
        for (int r = 0; r < 4; ++r) {
            const int q = kg * 4 + r;
            const float val = (vs + oacc[r]) / (4096.f + den_lds[q]);
            out[((size_t)(b * NN + n0 + q)) * HD + w * 16 + m] = val;
        }
    }
}

// ---------------------------------------------------------------------------
extern "C" void kernel_launch(void* const* d_in, const int* in_sizes, int n_in,
                              void* d_out, int out_size, void* d_ws, size_t ws_size,
                              hipStream_t stream)
{
    const float* x  = (const float*)d_in[0];
    const float* Wq = (const float*)d_in[1];
    const float* bq = (const float*)d_in[2];
    const float* Wk = (const float*)d_in[3];
    const float* bk = (const float*)d_in[4];
    const float* Wv = (const float*)d_in[5];
    const float* bv = (const float*)d_in[6];
    float* out = (float*)d_out;

    char* ws = (char*)d_ws;
    float*          Vs   = (float*)(ws + 0);                  //      512 B
    unsigned short* Khi  = (unsigned short*)(ws + 512);       // 1097728 B
    unsigned short* Klo  = (unsigned short*)(ws + 1098240);   // 1097728 B
    unsigned short* Qhi  = (unsigned short*)(ws + 2195968);   // 1048576 B
    unsigned short* Qlo  = (unsigned short*)(ws + 3244544);   // 1048576 B
    unsigned short* Wfhi = (unsigned short*)(ws + 4359168);   //  196608 B
    unsigned short* Wflo = (unsigned short*)(ws + 4555776);   //  196608 B
    unsigned short* Vfhi = (unsigned short*)(ws + 4752384);   //   51200 B
    unsigned short* Vflo = (unsigned short*)(ws + 4803584);   //   51200 B

    wprep_kernel<<<48, 256, 0, stream>>>(Wq, Wk, Wv, Wfhi, Wflo,
                                         Khi, Klo, Vfhi, Vflo, Vs);
    proj_kernel<<<128, 512, 0, stream>>>(x, Wfhi, Wflo, bq, bk, bv,
                                         Qhi, Qlo, Khi, Klo, Vfhi, Vflo, Vs);
    attn_kernel<<<512, 256, 0, stream>>>(Qhi, Qlo, Khi, Klo, Vfhi, Vflo, Vs, out);
}

// Round 9
// 97.801 us; speedup vs baseline: 1.2174x; 1.2174x over previous
//
#include <hip/hip_runtime.h>

typedef _Float16 half8 __attribute__((ext_vector_type(8)));
typedef float f32x4 __attribute__((ext_vector_type(4)));

#define NN 4096
#define NE 512
#define HD 64
#define KROWS 4288   // 64 pad + 4096 + 128 pad (per batch)
#define KOFF  64
#define WSCALE (1.0f / 256.0f)

// --- f16 helpers: RN hi + RN residual lo; hi+lo == f to ~2^-23 rel ---
__device__ __forceinline__ void f16_split(float f, _Float16& hi, _Float16& lo) {
    hi = (_Float16)f;                    // v_cvt_f16_f32 (round-to-nearest)
    lo = (_Float16)(f - (float)hi);
}

#define MFMA16(a, b, c) __builtin_amdgcn_mfma_f32_16x16x32_f16((a), (b), (c), 0, 0, 0)

// ---------------------------------------------------------------------------
// wprep: (a) W=[Wq|Wk|Wv] (512x192) -> B-frag order, f16 RN (hi only —
//        2-pass scheme; B-side RN error 2^-12 vs bf16-trunc 2^-9).
//        (b) zero K pad rows + Vs.  (c) Vf init: zeros + f16 ones plane nt=4.
// W frag layout: [kt(16)][nt(12)][lane(64)][j(8)]
// Vf layout:     [b(2)][jt(5)][nt(5)][lane(64)][jj(8)]
// ---------------------------------------------------------------------------
__global__ __launch_bounds__(256) void wprep_kernel(
    const float* __restrict__ Wq, const float* __restrict__ Wk,
    const float* __restrict__ Wv,
    _Float16* __restrict__ Wf, _Float16* __restrict__ Khi,
    _Float16* __restrict__ Vf, float* __restrict__ Vs)
{
    const int gtid = blockIdx.x * 256 + threadIdx.x;   // [0, 12288)
    const int L = gtid & 63;
    {
        const int nt = (gtid >> 6) % 12;
        const int kt = gtid / 768;
        const int n = nt * 16 + (L & 15);
        const int kbase = kt * 32 + (L >> 4) * 8;
        const float* src; int col;
        if (n < 64)       { src = Wq; col = n; }
        else if (n < 128) { src = Wk; col = n - 64; }
        else              { src = Wv; col = n - 128; }
        half8 sh;
#pragma unroll
        for (int j = 0; j < 8; ++j)
            sh[j] = (_Float16)src[(size_t)(kbase + j) * HD + col];
        *(half8*)(Wf + (size_t)gtid * 8) = sh;
    }
    if (gtid < 6144) {   // zero 768 pad rows x 128 B
        const int p = gtid >> 3, o = gtid & 7;
        const int b = p / 192, q = p - b * 192;
        const size_t row = (size_t)b * KROWS + (q < 64 ? q : 4096 + q);
        const half8 z = {0, 0, 0, 0, 0, 0, 0, 0};
        *(half8*)(Khi + row * HD + o * 8) = z;
    }
    if (gtid < 3200) {   // Vf init: zeros; nt==4 plane gets ones-pattern
        const int rem = gtid % 1600;
        const int jt = rem / 320;
        const int nt = (rem / 64) % 5;
        half8 sh = {0, 0, 0, 0, 0, 0, 0, 0};
        if (nt == 4 && (L & 15) == 0) {
#pragma unroll
            for (int jj = 0; jj < 8; ++jj) {
                const int j = jt * 32 + (L >> 4) * 8 + jj;
                if (j < 129) sh[jj] = (_Float16)1.0f;
            }
        }
        *(half8*)(Vf + (size_t)gtid * 8) = sh;
    }
    if (gtid < 128) Vs[gtid] = 0.f;
}

// ---------------------------------------------------------------------------
// proj: QKV = x @ W + b, 2-pass f16 MFMA ((xhi + xlo) * Whi-RN).
// grid 512 x 512 (8 waves) = 4096 waves = 16/CU (2x round 7 TLP).
// Block = 16 rows. Wave = nt-triple (w&3) x k-half (w>>2, 8 kt each);
// k-split partials combined via LDS. No manual prefetch (compiler sinks
// it anyway — TLP is the latency hider, proven rounds 5/7/8).
// Epilogue (waves 0-3): Q f16 hi+lo, K f16 hi, V -> LDS -> Vsum + V-frags.
// ---------------------------------------------------------------------------
__global__ __launch_bounds__(512) void proj_kernel(
    const float* __restrict__ x, const _Float16* __restrict__ Wf,
    const float* __restrict__ bq, const float* __restrict__ bk,
    const float* __restrict__ bv,
    _Float16* __restrict__ Qhi, _Float16* __restrict__ Qlo,
    _Float16* __restrict__ Khi, _Float16* __restrict__ Vf,
    float* __restrict__ Vs)
{
    __shared__ float parts[4][3][64][4];   // k-half-1 partials (12 KB)
    __shared__ float V_lds[16][68];
    const int tid = threadIdx.x;
    const int L = tid & 63;
    const int w = tid >> 6;              // wave 0..7
    const int m = L & 15, kg = L >> 4;
    const int blk = blockIdx.x;          // 0..511
    const int r0 = blk * 16;
    const int b = blk >> 8;
    const int t3 = w & 3;                // nt-triple: nts 3*t3..3*t3+2
    const int h = w >> 2;                // k-half: kts 8h..8h+7

    const float* xp = x + (size_t)(r0 + m) * NE + h * 256 + kg * 8;
    const _Float16* wfb = Wf + ((size_t)(h * 8) * 12 + t3 * 3) * 512 + L * 8;

    f32x4 acc[3];
#pragma unroll
    for (int t = 0; t < 3; ++t) acc[t] = (f32x4){0.f, 0.f, 0.f, 0.f};

#pragma unroll
    for (int kt = 0; kt < 8; ++kt) {
        const float4 x0 = *(const float4*)(xp + kt * 32);
        const float4 x1 = *(const float4*)(xp + kt * 32 + 4);
        const float xv[8] = {x0.x, x0.y, x0.z, x0.w, x1.x, x1.y, x1.z, x1.w};
        half8 ahi, alo;
#pragma unroll
        for (int j = 0; j < 8; ++j) {
            _Float16 hh, ll; f16_split(xv[j], hh, ll);
            ahi[j] = hh; alo[j] = ll;
        }
#pragma unroll
        for (int t = 0; t < 3; ++t) {
            const half8 wv = *(const half8*)(wfb + (size_t)kt * 6144 + t * 512);
            acc[t] = MFMA16(ahi, wv, acc[t]);
            acc[t] = MFMA16(alo, wv, acc[t]);
        }
    }

    if (h == 1) {
#pragma unroll
        for (int t = 0; t < 3; ++t)
            *(f32x4*)(&parts[t3][t][L][0]) = acc[t];
    }
    __syncthreads();

    if (h == 0) {
#pragma unroll
        for (int t = 0; t < 3; ++t) {
            const f32x4 p = *(const f32x4*)(&parts[t3][t][L][0]);
            acc[t] += p;
            const int nt = t3 * 3 + t;
            const int cgc = nt * 16 + m;     // global col 0..191
            const float bias = (cgc < 64) ? bq[cgc]
                             : (cgc < 128) ? bk[cgc - 64] : bv[cgc - 128];
#pragma unroll
            for (int r = 0; r < 4; ++r) {
                const int gr = r0 + kg * 4 + r;
                const float val = acc[t][r] + bias;
                if (cgc < 64) {
                    _Float16 hh, ll; f16_split(val, hh, ll);
                    Qhi[(size_t)gr * HD + cgc] = hh;
                    Qlo[(size_t)gr * HD + cgc] = ll;
                } else if (cgc < 128) {
                    const int d = cgc - 64, n = gr & 4095;
                    Khi[((size_t)b * KROWS + KOFF + n) * HD + d] = (_Float16)val;
                } else {
                    V_lds[kg * 4 + r][cgc - 128] = val;
                }
            }
        }
    }
    __syncthreads();

    // Vsum: one atomic per dim
    if (tid < 64) {
        float s = 0.f;
#pragma unroll
        for (int r = 0; r < 16; ++r) s += V_lds[r][tid];
        atomicAdd(&Vs[b * HD + tid], s);
    }

    // V-frag emission for rows < 129 (16-row blocks: local 0..7 -> two
    // kg-chunks of jt=local>>1; local 8 -> j==128 only).
    {
        const int local = blk & 255;
        if (local < 8 && w < 4) {
            const int jt = local >> 1;
            if ((kg >> 1) == (local & 1)) {   // this block owns kg chunk pair
                const int nt = w;             // V ntile 0..3
                half8 sh;
#pragma unroll
                for (int jj = 0; jj < 8; ++jj) {
                    const int lrow = (kg - (local & 1) * 2) * 8 + jj;  // 0..15
                    sh[jj] = (_Float16)V_lds[lrow][nt * 16 + m];
                }
                const size_t fo = ((size_t)((b * 25 + jt * 5 + nt) * 64 + L)) * 8;
                *(half8*)(Vf + fo) = sh;
            }
        } else if (local == 8 && w < 4 && kg == 0) {
            const int nt = w;
            half8 sh = {0, 0, 0, 0, 0, 0, 0, 0};
            sh[0] = (_Float16)V_lds[0][nt * 16 + m];   // j == 128
            const size_t fo = ((size_t)((b * 25 + 4 * 5 + nt) * 64 + L)) * 8;
            *(half8*)(Vf + fo) = sh;
        }
    }
}

// ---------------------------------------------------------------------------
// attn: grid 512 (b = blk>>8, 16 queries/block), block 256 (4 waves).
// f16 2-pass. ALL global loads issued up front -> one latency hop.
// Phase 1: S = (qhi+qlo).Khi^T (2-pass), w' = (exp(s)-1)/256 -> LDS f16
// hi/lo (scaled to dodge f16 overflow at s>11; exact unscale in epilogue).
// Phase 2: [out|den] = wt(16x160) @ [V|1|0] (2-pass); wave wv owns ntile
// wv; wave 0 also the ones-column tile.
// ---------------------------------------------------------------------------
__global__ __launch_bounds__(256) void attn_kernel(
    const _Float16* __restrict__ Qhi, const _Float16* __restrict__ Qlo,
    const _Float16* __restrict__ Khi, const _Float16* __restrict__ Vf,
    const float* __restrict__ Vs, float* __restrict__ out)
{
    __shared__ __align__(16) _Float16 wt_hi[16 * 168];
    __shared__ __align__(16) _Float16 wt_lo[16 * 168];
    __shared__ float den_lds[16];

    const int tid = threadIdx.x;
    const int L = tid & 63;
    const int w = tid >> 6;
    const int m = L & 15, kg = L >> 4;
    const int b = blockIdx.x >> 8;
    const int n0 = (blockIdx.x & 255) * 16;

    // ---- upfront load issuance (all independent) ----
    const _Float16* qp  = Qhi + ((size_t)(b * NN + n0 + m)) * HD + kg * 8;
    const _Float16* qp2 = Qlo + ((size_t)(b * NN + n0 + m)) * HD + kg * 8;
    const half8 qhi0 = *(const half8*)(qp);
    const half8 qhi1 = *(const half8*)(qp + 32);
    const half8 qlo0 = *(const half8*)(qp2);
    const half8 qlo1 = *(const half8*)(qp2 + 32);

    int kts[3]; int nkt;
    if (w == 3) { kts[0] = 3; kts[1] = 7; kts[2] = 8; nkt = 3; }
    else        { kts[0] = w; kts[1] = w + 4; kts[2] = 0; nkt = 2; }

    const _Float16* KB = Khi + (size_t)b * KROWS * HD;
    half8 kh0[3], kh1[3];
#pragma unroll
    for (int i = 0; i < 3; ++i) {
        if (i < nkt) {                   // wave-uniform branch
            const _Float16* kp = KB + (size_t)(n0 + kts[i] * 16 + m) * HD + kg * 8;
            kh0[i] = *(const half8*)(kp);
            kh1[i] = *(const half8*)(kp + 32);
        }
    }

    half8 vhi[5], vh4[5];
#pragma unroll
    for (int jt = 0; jt < 5; ++jt) {
        const size_t fo = ((size_t)((b * 25 + jt * 5 + w) * 64 + L)) * 8;
        vhi[jt] = *(const half8*)(Vf + fo);
    }
    if (w == 0) {                        // wave-uniform
#pragma unroll
        for (int jt = 0; jt < 5; ++jt) {
            const size_t fo4 = ((size_t)((b * 25 + jt * 5 + 4) * 64 + L)) * 8;
            vh4[jt] = *(const half8*)(Vf + fo4);
        }
    }

    // zero the (q,j) weight buffer (j in [129,168) must read as 0)
    for (int i = tid; i < (16 * 168) / 2; i += 256) {
        ((int*)wt_hi)[i] = 0;
        ((int*)wt_lo)[i] = 0;
    }
    __syncthreads();

    // ---- phase 1 ----
#pragma unroll
    for (int i = 0; i < 3; ++i) {
        if (i < nkt) {
            f32x4 acc = (f32x4){0.f, 0.f, 0.f, 0.f};
            acc = MFMA16(qhi0, kh0[i], acc);
            acc = MFMA16(qhi1, kh1[i], acc);
            acc = MFMA16(qlo0, kh0[i], acc);
            acc = MFMA16(qlo1, kh1[i], acc);
            const int l = kts[i] * 16 + m;
#pragma unroll
            for (int r = 0; r < 4; ++r) {
                const int q = kg * 4 + r;
                const int j = l - q;
                if (j >= 0 && j < 129) {
                    const float wval = (__expf(acc[r]) - 1.0f) * WSCALE;
                    _Float16 hh, ll; f16_split(wval, hh, ll);
                    wt_hi[q * 168 + j] = hh;
                    wt_lo[q * 168 + j] = ll;
                }
            }
        }
    }
    __syncthreads();

    // ---- phase 2 ----
    f32x4 oacc = (f32x4){0.f, 0.f, 0.f, 0.f};
    f32x4 dacc = (f32x4){0.f, 0.f, 0.f, 0.f};
#pragma unroll
    for (int jt = 0; jt < 5; ++jt) {
        const half8 whi = *(const half8*)(wt_hi + m * 168 + jt * 32 + kg * 8);
        const half8 wlo = *(const half8*)(wt_lo + m * 168 + jt * 32 + kg * 8);
        oacc = MFMA16(whi, vhi[jt], oacc);
        oacc = MFMA16(wlo, vhi[jt], oacc);
        if (w == 0) {
            dacc = MFMA16(whi, vh4[jt], dacc);
            dacc = MFMA16(wlo, vh4[jt], dacc);
        }
    }
    if (w == 0 && m == 0) {
#pragma unroll
        for (int r = 0; r < 4; ++r) den_lds[kg * 4 + r] = dacc[r];
    }
    __syncthreads();

    // ---- epilogue (unscale: num = 256*oacc, den = 4096 + 256*dacc) ----
    {
        const float vs = Vs[b * HD + w * 16 + m];
#pragma unroll
        for (int r = 0; r < 4; ++r) {
            const int q = kg * 4 + r;
            const float val = (vs + 256.0f * oacc[r])
                            / (4096.f + 256.0f * den_lds[q]);
            out[((size_t)(b * NN + n0 + q)) * HD + w * 16 + m] = val;
        }
    }
}

// ---------------------------------------------------------------------------
extern "C" void kernel_launch(void* const* d_in, const int* in_sizes, int n_in,
                              void* d_out, int out_size, void* d_ws, size_t ws_size,
                              hipStream_t stream)
{
    const float* x  = (const float*)d_in[0];
    const float* Wq = (const float*)d_in[1];
    const float* bq = (const float*)d_in[2];
    const float* Wk = (const float*)d_in[3];
    const float* bk = (const float*)d_in[4];
    const float* Wv = (const float*)d_in[5];
    const float* bv = (const float*)d_in[6];
    float* out = (float*)d_out;

    char* ws = (char*)d_ws;
    float*     Vs  = (float*)(ws + 0);              //      512 B
    _Float16*  Khi = (_Float16*)(ws + 512);         // 1097728 B
    _Float16*  Qhi = (_Float16*)(ws + 1098240);     // 1048576 B
    _Float16*  Qlo = (_Float16*)(ws + 2146816);     // 1048576 B
    _Float16*  Wf  = (_Float16*)(ws + 3195392);     //  196608 B
    _Float16*  Vf  = (_Float16*)(ws + 3392000);     //   51200 B

    wprep_kernel<<<48, 256, 0, stream>>>(Wq, Wk, Wv, Wf, Khi, Vf, Vs);
    proj_kernel<<<512, 512, 0, stream>>>(x, Wf, bq, bk, bv,
                                         Qhi, Qlo, Khi, Vf, Vs);
    attn_kernel<<<512, 256, 0, stream>>>(Qhi, Qlo, Khi, Vf, Vs, out);
}